// Round 1
// baseline (131.146 us; speedup 1.0000x reference)
//
#include <hip/hip_runtime.h>
#include <math.h>

#define SEQ   576     // H*W = 24*24
#define CDIM  96
#define INNER 192
#define NHEAD 48
#define DH    4
#define NB    2
#define EPSV  1e-5f

__device__ __forceinline__ float silu_f(float x) { return x / (1.f + __expf(-x)); }
__device__ __forceinline__ float logsig_f(float x) {
    // log(sigmoid(x)) = -softplus(-x), numerically stable
    return (x >= 0.f) ? -log1pf(__expf(-x)) : (x - log1pf(__expf(x)));
}

// ---------------- Kernel A: LayerNorm + up-projection (96 -> 384) ----------------
__global__ void k_ln_up(const float* __restrict__ x, const float* __restrict__ ln_g,
                        const float* __restrict__ ln_b, const float* __restrict__ w_up,
                        const float* __restrict__ b_up,
                        float* __restrict__ xm, float* __restrict__ z) {
    const int bs = blockIdx.x;                 // 0..NB*SEQ-1
    const int b = bs / SEQ, s = bs % SEQ;
    const int t = threadIdx.x;                 // 128 threads
    __shared__ float red[128];
    __shared__ float hbuf[CDIM];

    float val = 0.f;
    if (t < CDIM) val = x[(size_t)(b * CDIM + t) * SEQ + s];
    red[t] = val;
    __syncthreads();
    for (int off = 64; off > 0; off >>= 1) { if (t < off) red[t] += red[t + off]; __syncthreads(); }
    const float mean = red[0] * (1.f / CDIM);
    __syncthreads();
    float d = (t < CDIM) ? (val - mean) : 0.f;
    red[t] = d * d;
    __syncthreads();
    for (int off = 64; off > 0; off >>= 1) { if (t < off) red[t] += red[t + off]; __syncthreads(); }
    const float rstd = rsqrtf(red[0] * (1.f / CDIM) + EPSV);
    if (t < CDIM) hbuf[t] = (val - mean) * rstd * ln_g[t] + ln_b[t];
    __syncthreads();

    for (int f = t; f < 2 * INNER; f += 128) {
        float acc = b_up[f];
        const float* wr = w_up + (size_t)f * CDIM;
        #pragma unroll 8
        for (int c = 0; c < CDIM; ++c) acc += hbuf[c] * wr[c];
        if (f < INNER) xm[(size_t)(b * SEQ + s) * INNER + f] = acc;
        else           z [(size_t)(b * SEQ + s) * INNER + (f - INNER)] = acc;
    }
}

// ------------- Kernel B: causal conv + SiLU, headwise q/k/v, ig/fg gates -------------
__global__ void k_conv_qkv_gates(const float* __restrict__ xm,
    const float* __restrict__ w_conv, const float* __restrict__ b_conv,
    const float* __restrict__ w_q, const float* __restrict__ b_q,
    const float* __restrict__ w_k, const float* __restrict__ b_k,
    const float* __restrict__ w_v, const float* __restrict__ b_v,
    const float* __restrict__ w_ig, const float* __restrict__ b_ig,
    const float* __restrict__ w_fg, const float* __restrict__ b_fg,
    float* __restrict__ xc, float* __restrict__ qw, float* __restrict__ kw,
    float* __restrict__ vw, float* __restrict__ igw, float* __restrict__ fgw) {
    const int bs = blockIdx.x;
    const int b = bs / SEQ, s = bs % SEQ;
    const int t = threadIdx.x;   // 192 threads
    __shared__ float xc_l[INNER], xm_l[INNER], qkv_l[3 * INNER];

    // depthwise causal conv K=4 (cross-correlation, left pad 3) + SiLU
    {
        float acc = b_conv[t];
        #pragma unroll
        for (int j = 0; j < 4; ++j) {
            int ss = s - 3 + j;
            if (ss >= 0) acc += xm[(size_t)(b * SEQ + ss) * INNER + t] * w_conv[t * 4 + j];
        }
        float v = silu_f(acc);
        xc_l[t] = v;
        xc[(size_t)(b * SEQ + s) * INNER + t] = v;
        xm_l[t] = xm[(size_t)(b * SEQ + s) * INNER + t];
    }
    __syncthreads();
    // headwise 4x4 projections
    {
        const int n = t >> 2, o = t & 3;
        const float* wq = w_q + n * 16 + o * 4;
        const float* wk = w_k + n * 16 + o * 4;
        const float* wv = w_v + n * 16 + o * 4;
        float q = b_q[t], k = b_k[t], v = b_v[t];
        #pragma unroll
        for (int dd = 0; dd < 4; ++dd) {
            q += xc_l[n * 4 + dd] * wq[dd];
            k += xc_l[n * 4 + dd] * wk[dd];
            v += xm_l[n * 4 + dd] * wv[dd];
        }
        qkv_l[t] = q; qkv_l[INNER + t] = k; qkv_l[2 * INNER + t] = v;
        size_t base = ((size_t)(b * NHEAD + n) * SEQ + s) * DH + o;
        qw[base] = q; kw[base] = k; vw[base] = v;
    }
    __syncthreads();
    // ig/fg: dot over the 576-long qkv row
    if (t < 2 * NHEAD) {
        const int h = t % NHEAD;
        const bool isfg = (t >= NHEAD);
        const float* w = (isfg ? w_fg : w_ig) + (size_t)h * 3 * INNER;
        float acc = isfg ? b_fg[h] : b_ig[h];
        for (int f = 0; f < 3 * INNER; ++f) acc += qkv_l[f] * w[f];
        (isfg ? fgw : igw)[(size_t)(b * NHEAD + h) * SEQ + s] = acc;
    }
}

// ------------- Kernel C: mLSTM parallel stabilized (per (b,head) block) -------------
// key identity: Dm[s,t] = exp(m[t] - M[s]) with m[t] = ig[t] - lf_cum[t+1],
//               M[s] = prefix-max(m)[s];  max_log_D[s] = lf_cum[s+1] + M[s]
__global__ void __launch_bounds__(256) k_mlstm(const float* __restrict__ qw,
    const float* __restrict__ kw, const float* __restrict__ vw,
    const float* __restrict__ igw, const float* __restrict__ fgw,
    float* __restrict__ ht) {
    const int bh = blockIdx.x;   // 0..NB*NHEAD-1
    const int t = threadIdx.x;   // 256 threads
    __shared__ float k_l[SEQ * DH], v_l[SEQ * DH];
    __shared__ float m_l[SEQ], lfc_l[SEQ], M_l[SEQ];

    const float* kb = kw + (size_t)bh * SEQ * DH;
    const float* vb = vw + (size_t)bh * SEQ * DH;
    const float* qb = qw + (size_t)bh * SEQ * DH;

    for (int i = t; i < SEQ * DH; i += 256) { k_l[i] = kb[i]; v_l[i] = vb[i]; }
    for (int i = t; i < SEQ; i += 256) {
        M_l[i] = logsig_f(fgw[(size_t)bh * SEQ + i]);   // temp: log_f
        m_l[i] = igw[(size_t)bh * SEQ + i];             // temp: ig
    }
    __syncthreads();

    if (t < 64) {                // wave-0 chunked scans: 64 lanes x 9 elems = 576
        const int base = t * 9;
        float pre[9], mv[9], mx[9];
        float run = 0.f;
        #pragma unroll
        for (int j = 0; j < 9; ++j) { run += M_l[base + j]; pre[j] = run; }
        float incl = run;
        #pragma unroll
        for (int off = 1; off < 64; off <<= 1) {
            float o = __shfl_up(incl, off);
            if (t >= off) incl += o;
        }
        const float excl = incl - run;                  // exclusive prefix of lane sums
        float runm = -INFINITY;
        #pragma unroll
        for (int j = 0; j < 9; ++j) {
            float lfc = excl + pre[j];                  // lf_cum[t+1]
            lfc_l[base + j] = lfc;
            float mt = m_l[base + j] - lfc;             // ig[t] - lf_cum[t+1]
            mv[j] = mt;
            runm = fmaxf(runm, mt);
            mx[j] = runm;
        }
        float sc = runm;
        #pragma unroll
        for (int off = 1; off < 64; off <<= 1) {
            float o = __shfl_up(sc, off);
            if (t >= off) sc = fmaxf(sc, o);
        }
        float exclm = __shfl_up(sc, 1);
        if (t == 0) exclm = -INFINITY;
        #pragma unroll
        for (int j = 0; j < 9; ++j) {
            m_l[base + j] = mv[j];
            M_l[base + j] = fmaxf(exclm, mx[j]);
        }
    }
    __syncthreads();

    for (int s0 = t; s0 < SEQ; s0 += 256) {
        const float q0 = qb[s0 * 4], q1 = qb[s0 * 4 + 1], q2 = qb[s0 * 4 + 2], q3 = qb[s0 * 4 + 3];
        const float Ms = M_l[s0], lfcs = lfc_l[s0];
        float a0 = 0.f, a1 = 0.f, a2 = 0.f, a3 = 0.f, csum = 0.f;
        for (int tt = 0; tt <= s0; ++tt) {
            float e = __expf(m_l[tt] - Ms);
            float qk = (q0 * k_l[tt * 4] + q1 * k_l[tt * 4 + 1] +
                        q2 * k_l[tt * 4 + 2] + q3 * k_l[tt * 4 + 3]) * 0.5f;   // DH^-0.5
            float c = qk * e;
            csum += c;
            a0 += c * v_l[tt * 4];     a1 += c * v_l[tt * 4 + 1];
            a2 += c * v_l[tt * 4 + 2]; a3 += c * v_l[tt * 4 + 3];
        }
        const float floorv = __expf(-(lfcs + Ms));      // exp(-max_log_D[s])
        const float inv = 1.f / (fmaxf(fabsf(csum), floorv) + 1e-6f);
        size_t ob = ((size_t)bh * SEQ + s0) * 4;
        ht[ob] = a0 * inv; ht[ob + 1] = a1 * inv; ht[ob + 2] = a2 * inv; ht[ob + 3] = a3 * inv;
    }
}

// ------------- Kernel D: per-head LN, skip, z-gate, down-proj, residual -------------
__global__ void k_epilogue(const float* __restrict__ ht, const float* __restrict__ on_g,
    const float* __restrict__ on_b, const float* __restrict__ skip,
    const float* __restrict__ xc, const float* __restrict__ z,
    const float* __restrict__ w_down, const float* __restrict__ b_down,
    const float* __restrict__ x, float* __restrict__ out) {
    const int bs = blockIdx.x;
    const int b = bs / SEQ, s = bs % SEQ;
    const int t = threadIdx.x;   // 192 threads
    __shared__ float ht_l[INNER], hs_l[INNER];
    const int n = t >> 2;

    ht_l[t] = ht[((size_t)(b * NHEAD + n) * SEQ + s) * DH + (t & 3)];
    __syncthreads();
    const float h0 = ht_l[n * 4], h1 = ht_l[n * 4 + 1], h2 = ht_l[n * 4 + 2], h3 = ht_l[n * 4 + 3];
    const float mean = (h0 + h1 + h2 + h3) * 0.25f;
    const float d0 = h0 - mean, d1 = h1 - mean, d2 = h2 - mean, d3 = h3 - mean;
    const float var = (d0 * d0 + d1 * d1 + d2 * d2 + d3 * d3) * 0.25f;
    const float rstd = rsqrtf(var + EPSV);
    const float hn = (ht_l[t] - mean) * rstd * on_g[t] + on_b[t];
    const float hskip = hn + skip[t] * xc[(size_t)(b * SEQ + s) * INNER + t];
    const float zv = z[(size_t)(b * SEQ + s) * INNER + t];
    hs_l[t] = hskip * silu_f(zv);
    __syncthreads();

    if (t < CDIM) {
        float acc = b_down[t];
        const float* wr = w_down + (size_t)t * INNER;
        #pragma unroll 8
        for (int d = 0; d < INNER; ++d) acc += hs_l[d] * wr[d];
        size_t idx = ((size_t)b * CDIM + t) * SEQ + s;
        out[idx] = x[idx] + acc;
    }
}

extern "C" void kernel_launch(void* const* d_in, const int* in_sizes, int n_in,
                              void* d_out, int out_size, void* d_ws, size_t ws_size,
                              hipStream_t stream) {
    const float* x      = (const float*)d_in[0];
    const float* ln_g   = (const float*)d_in[1];
    const float* ln_b   = (const float*)d_in[2];
    const float* w_up   = (const float*)d_in[3];
    const float* b_up   = (const float*)d_in[4];
    const float* w_q    = (const float*)d_in[5];
    const float* b_q    = (const float*)d_in[6];
    const float* w_k    = (const float*)d_in[7];
    const float* b_k    = (const float*)d_in[8];
    const float* w_v    = (const float*)d_in[9];
    const float* b_v    = (const float*)d_in[10];
    const float* w_conv = (const float*)d_in[11];
    const float* b_conv = (const float*)d_in[12];
    const float* w_ig   = (const float*)d_in[13];
    const float* b_ig   = (const float*)d_in[14];
    const float* w_fg   = (const float*)d_in[15];
    const float* b_fg   = (const float*)d_in[16];
    const float* on_g   = (const float*)d_in[17];
    const float* on_b   = (const float*)d_in[18];
    const float* skip   = (const float*)d_in[19];
    const float* w_down = (const float*)d_in[20];
    const float* b_down = (const float*)d_in[21];

    float* ws = (float*)d_ws;
    const size_t NSI = (size_t)NB * SEQ * INNER;       // 221184
    float* xm = ws;                 // x_mlstm   [B][S][192]
    float* z  = xm + NSI;           // z         [B][S][192]
    float* xc = z + NSI;            // x_conv    [B][S][192]
    float* qw = xc + NSI;           // q         [B][NH][S][4]
    float* kw = qw + NSI;
    float* vw = kw + NSI;
    float* igw = vw + NSI;          // ig        [B][NH][S]
    float* fgw = igw + (size_t)NB * NHEAD * SEQ;
    float* ht  = fgw + (size_t)NB * NHEAD * SEQ;       // h_tilde [B][NH][S][4]
    // total: 7*221184 + 2*55296 = 1,658,880 floats = 6.6 MB

    float* out = (float*)d_out;

    dim3 gBS(NB * SEQ);
    hipLaunchKernelGGL(k_ln_up, gBS, dim3(128), 0, stream, x, ln_g, ln_b, w_up, b_up, xm, z);
    hipLaunchKernelGGL(k_conv_qkv_gates, gBS, dim3(192), 0, stream, xm, w_conv, b_conv,
                       w_q, b_q, w_k, b_k, w_v, b_v, w_ig, b_ig, w_fg, b_fg,
                       xc, qw, kw, vw, igw, fgw);
    hipLaunchKernelGGL(k_mlstm, dim3(NB * NHEAD), dim3(256), 0, stream,
                       qw, kw, vw, igw, fgw, ht);
    hipLaunchKernelGGL(k_epilogue, gBS, dim3(192), 0, stream, ht, on_g, on_b, skip,
                       xc, z, w_down, b_down, x, out);
}